// Round 20
// baseline (330.948 us; speedup 1.0000x reference)
//
#include <hip/hip_runtime.h>

typedef short bf16x8 __attribute__((ext_vector_type(8)));
typedef float f32x4 __attribute__((ext_vector_type(4)));
typedef float f32x2 __attribute__((ext_vector_type(2)));
typedef unsigned short u16;
typedef unsigned int u32;
typedef unsigned char u8;

#define NN 100000
#define NE 600000
#define PART 12500        // NN / 8
#define NB 250            // phase-A blocks per relation
#define CA 2400           // NE / NB edges per A-block (= sub-region capacity)

__device__ __forceinline__ u16 f2b(float f) {
    u32 u = __float_as_uint(f);
    return (u16)((u + 0x7FFFu + ((u >> 16) & 1u)) >> 16);
}

// ---------------- phase A: bucket edges by dst partition (single pass) ----------------
// Each block owns exclusive sub-regions stg[(rel*NB+b)*8+part][0..CA) -> no global
// atomics, no cross-block line sharing. Entry: lo=(src<<15)|ew15, hi=dst.
__global__ __launch_bounds__(256) void bucket_edges(
    const int* __restrict__ src0, const int* __restrict__ dst0,
    const float* __restrict__ ew0,
    const int* __restrict__ src1, const int* __restrict__ dst1,
    const float* __restrict__ ew1,
    uint2* __restrict__ stg, int* __restrict__ cnt)
{
    int rel = blockIdx.x >= NB;
    int b = blockIdx.x - rel * NB;
    const int* src = rel ? src1 : src0;
    const int* dst = rel ? dst1 : dst0;
    const float* ew = rel ? ew1 : ew0;
    __shared__ int lcur[8];
    if (threadIdx.x < 8) lcur[threadIdx.x] = 0;
    __syncthreads();
    uint2* base = stg + (size_t)((rel * NB + b) * 8) * CA;
    const int e0 = b * CA;
    for (int e = e0 + threadIdx.x; e < e0 + CA; e += 256) {
        int d = dst[e];
        int part = d / PART;
        u32 q = (__float_as_uint(ew[e]) + 0x10000u) >> 17;
        u32 lo = ((u32)src[e] << 15) | q;
        int pos = atomicAdd(&lcur[part], 1);
        base[part * CA + pos] = make_uint2(lo, (u32)d);
    }
    __syncthreads();
    if (threadIdx.x < 8)
        cnt[(rel * NB + b) * 8 + threadIdx.x] = lcur[threadIdx.x];
}

// ---------------- phase B1: degree count from buckets (XCD-local atomics) ----------------
// 2048 co-resident blocks; part = bid&7 -> XCD-pinned; reads contiguous buckets.
__global__ __launch_bounds__(256) void deg_from_stg(
    const uint2* __restrict__ stg, const int* __restrict__ cnt,
    int* __restrict__ g0, int* __restrict__ g1)
{
    int part = blockIdx.x & 7;
    int sub = blockIdx.x >> 3;                // 0..255
    int rel = sub & 1, idx = sub >> 1;        // idx 0..127
    int* g = rel ? g1 : g0;
    for (int ab = idx * 2; ab < min(idx * 2 + 2, NB); ++ab) {
        int n = cnt[(rel * NB + ab) * 8 + part];
        const uint2* base = stg + (size_t)((rel * NB + ab) * 8 + part) * CA;
        for (int i = threadIdx.x; i < n; i += 256)
            atomicAdd(&g[base[i].y], 1);
    }
}

// ---------------- phase B2: place entries into CSR (XCD-local atomics) ----------------
__global__ __launch_bounds__(256) void place_csr(
    const uint2* __restrict__ stg, const int* __restrict__ cnt,
    int* __restrict__ cur0, int* __restrict__ cur1,
    u32* __restrict__ csr0, u32* __restrict__ csr1)
{
    int part = blockIdx.x & 7;
    int sub = blockIdx.x >> 3;
    int rel = sub & 1, idx = sub >> 1;
    int* cur = rel ? cur1 : cur0;
    u32* csr = rel ? csr1 : csr0;
    for (int ab = idx * 2; ab < min(idx * 2 + 2, NB); ++ab) {
        int n = cnt[(rel * NB + ab) * 8 + part];
        const uint2* base = stg + (size_t)((rel * NB + ab) * 8 + part) * CA;
        for (int i = threadIdx.x; i < n; i += 256) {
            uint2 en = base[i];
            int p = atomicAdd(&cur[en.y], 1);
            csr[p] = en.x;
        }
    }
}

// ---------------- fused setup: x->bf16 + x->fp8 | weight prep ----------------
__global__ void fused_setup(
    const float* __restrict__ x, u16* __restrict__ xo, u8* __restrict__ x8,
    const float* __restrict__ Ws0_0, const float* __restrict__ Ws0_1,
    const float* __restrict__ Wn0_0, const float* __restrict__ Wn0_1,
    const float* __restrict__ Wp_0,  const float* __restrict__ Wp_1,
    const float* __restrict__ Ws1_0, const float* __restrict__ Ws1_1,
    const float* __restrict__ Wn1_0, const float* __restrict__ Wn1_1,
    const float* __restrict__ b0_0, const float* __restrict__ b0_1,
    const float* __restrict__ b1_0, const float* __restrict__ b1_1,
    const float* __restrict__ bp_0, const float* __restrict__ bp_1,
    u16* __restrict__ w, float* __restrict__ bsum0, float* __restrict__ bsum1,
    float* __restrict__ bpc)
{
    int bb = blockIdx.x;
    if (bb < 12500) {                         // x conversions (NN*128/4 threads)
        int t = bb * 256 + threadIdx.x;
        const float4 v = reinterpret_cast<const float4*>(x)[t];
        ushort4 r; r.x = f2b(v.x); r.y = f2b(v.y); r.z = f2b(v.z); r.w = f2b(v.w);
        reinterpret_cast<ushort4*>(xo)[t] = r;
        u32 p = __builtin_amdgcn_cvt_pk_fp8_f32(v.x, v.y, 0, false);
        p = __builtin_amdgcn_cvt_pk_fp8_f32(v.z, v.w, p, true);
        reinterpret_cast<u32*>(x8)[t] = p;
    } else {                                  // weight prep (418 blocks)
        int t = (bb - 12500) * 256 + threadIdx.x;
        if (t < 81920) {                      // five 128x128 transposes
            int m = t >> 14, u = t & 16383;
            int n = u >> 7, k = u & 127;
            float v;
            if (m == 0)      v = Ws0_0[k * 128 + n] + Ws0_1[k * 128 + n];
            else if (m == 1) v = Wn0_0[k * 128 + n];
            else if (m == 2) v = Wn0_1[k * 128 + n];
            else if (m == 3) v = Wp_0[k * 128 + n];
            else             v = Wp_1[k * 128 + n];
            w[t] = f2b(v);
        } else if (t < 106496) {              // three 64x128 transposed
            int u = t - 81920;
            int m = u >> 13; u &= 8191;
            int n = u >> 7, k = u & 127;
            float v;
            if (m == 0)      v = Ws1_0[k * 64 + n] + Ws1_1[k * 64 + n];
            else if (m == 1) v = Wn1_0[k * 64 + n];
            else             v = Wn1_1[k * 64 + n];
            w[t] = f2b(v);
        } else if (t < 106624) {
            int i = t - 106496; bsum0[i] = b0_0[i] + b0_1[i];
        } else if (t < 106688) {
            int i = t - 106624; bsum1[i] = b1_0[i] + b1_1[i];
        } else if (t < 106944) {
            int i = t - 106688; bpc[i] = (i < 128) ? bp_0[i] : bp_1[i - 128];
        }
    }
}

// ---------------- prefix scan ----------------
__global__ void scan_local(const int* __restrict__ deg0, const int* __restrict__ deg1,
                           int* __restrict__ offs0, int* __restrict__ offs1,
                           int* __restrict__ bsA, int* __restrict__ bsB)
{
    __shared__ int sm[1024];
    int rel = blockIdx.x >= 98;
    int blk = blockIdx.x - rel * 98;
    const int* in = rel ? deg1 : deg0;
    int* out = rel ? offs1 : offs0;
    int* bsum = rel ? bsB : bsA;
    int t = threadIdx.x;
    int i = blk * 1024 + t;
    int v = (i < NN) ? in[i] : 0;
    sm[t] = v;
    __syncthreads();
    for (int off = 1; off < 1024; off <<= 1) {
        int add = (t >= off) ? sm[t - off] : 0;
        __syncthreads();
        sm[t] += add;
        __syncthreads();
    }
    if (i < NN) out[i] = sm[t] - v;            // exclusive
    if (t == 1023) bsum[blk] = sm[1023];
}

__global__ void scan_bsums(int* __restrict__ bsA, int* __restrict__ bsB)
{
    __shared__ int sm[128];
    int* bsum = blockIdx.x ? bsB : bsA;
    int t = threadIdx.x;
    int v = (t < 98) ? bsum[t] : 0;
    sm[t] = v;
    __syncthreads();
    for (int off = 1; off < 128; off <<= 1) {
        int add = (t >= off) ? sm[t - off] : 0;
        __syncthreads();
        sm[t] += add;
        __syncthreads();
    }
    if (t < 98) bsum[t] = sm[t] - v;           // exclusive
}

__global__ void scan_add(int* __restrict__ offs0, int* __restrict__ offs1,
                         const int* __restrict__ bsA, const int* __restrict__ bsB,
                         int* __restrict__ cur0, int* __restrict__ cur1,
                         u32* __restrict__ csr0, u32* __restrict__ csr1)
{
    int rel = blockIdx.x >= 392;
    int i = (blockIdx.x - rel * 392) * 256 + threadIdx.x;
    int* offs = rel ? offs1 : offs0;
    int* cur = rel ? cur1 : cur0;
    const int* bsum = rel ? bsB : bsA;
    if (i < NN) {
        int v = offs[i] + bsum[i >> 10];
        offs[i] = v;
        cur[i] = v;
    }
    if (i == 0) offs[NN] = NE;
    if (blockIdx.x == 0 && threadIdx.x < 8) {  // pads for gather unroll-8 over-read
        csr0[NE + threadIdx.x] = 0;
        csr1[NE + threadIdx.x] = 0;
    }
}

// ---------------- flat gather, wave per node, unroll-8 ----------------
// FP8: table rows 128B fp8 e4m3 (mean path); else bf16 256B rows (max path).
template<bool MAXAGG, bool FP8>
__global__ __launch_bounds__(256) void gather(
    const u8* __restrict__ F0, const u8* __restrict__ F1,
    const int* __restrict__ offs0, const u32* __restrict__ csr0, u16* __restrict__ o0,
    const int* __restrict__ offs1, const u32* __restrict__ csr1, u16* __restrict__ o1)
{
    int b = blockIdx.x;
    int rel = b >= 25000;
    const u8* F = rel ? F1 : F0;
    const int* offs = rel ? offs1 : offs0;
    const u32* csr = rel ? csr1 : csr0;
    u16* out = rel ? o1 : o0;
    int node = (b - rel * 25000) * 4 + (threadIdx.x >> 6);
    int lane2 = (threadIdx.x & 63) << 1;       // 2 features per lane
    int beg = __builtin_amdgcn_readfirstlane(offs[node]);
    int end = __builtin_amdgcn_readfirstlane(offs[node + 1]);

    float a0 = 0.f, a1 = 0.f;
    for (int e = beg; e < end; e += 8) {
        u32 E[8], v[8];
#pragma unroll
        for (int i = 0; i < 8; ++i)
            E[i] = csr[e + i];
#pragma unroll
        for (int i = 0; i < 8; ++i) {
            if (FP8)
                v[i] = *reinterpret_cast<const u16*>(F + ((size_t)(E[i] >> 15) << 7) + lane2);
            else
                v[i] = *reinterpret_cast<const u32*>(F + ((size_t)(E[i] >> 15) << 8) + (lane2 << 1));
        }
#pragma unroll
        for (int i = 0; i < 8; ++i) {
            float wgt = (e + i < end) ? __uint_as_float(E[i] << 17) : 0.f;
            float f0, f1;
            if (FP8) {
                f32x2 d = __builtin_amdgcn_cvt_pk_f32_fp8(v[i], false);
                f0 = d.x; f1 = d.y;
            } else {
                f0 = __uint_as_float(v[i] << 16);
                f1 = __uint_as_float(v[i] & 0xFFFF0000u);
            }
            if (MAXAGG) { a0 = fmaxf(a0, f0 * wgt); a1 = fmaxf(a1, f1 * wgt); }
            else        { a0 = fmaf(f0, wgt, a0);   a1 = fmaf(f1, wgt, a1); }
        }
    }
    float s = MAXAGG ? 1.f : 1.f / fmaxf((float)(end - beg), 1.f);
    ushort2 r; r.x = f2b(a0 * s); r.y = f2b(a1 * s);
    *reinterpret_cast<ushort2*>(out + (size_t)node * 128 + lane2) = r;
}

// ---------------- LDS-staged double-buffered MFMA GEMM ----------------
// A tiles staged via reg->LDS async split (issue loads before compute, ds_write after).
// XOR swizzle byte ^= (row&7)<<4: conflict-free write and strided ds_read_b128.
// RS = WAVES/COLGROUPS row-split: RS=1 -> each wave does both 16-row halves;
// RS=2 -> wave handles half rsub only.
template<int NPAIR, int COLGROUPS, int WAVES, bool RELU, bool OUTF32, bool DUAL>
__global__ __launch_bounds__(WAVES * 64) void gemm_lds(
    const u16* __restrict__ A0, const u16* __restrict__ A1, const u16* __restrict__ A2,
    const u16* __restrict__ BT, const float* __restrict__ bias,
    float* __restrict__ outF, u16* __restrict__ outB, u16* __restrict__ outB2)
{
    constexpr int NC = COLGROUPS * 32;
    constexpr int OST = DUAL ? (NC / 2) : NC;
    constexpr int NTILES = NN / 32;
    constexpr int THREADS = WAVES * 64;
    constexpr int NLOAD = NPAIR * 512 / THREADS;   // 16B slots per thread per tile
    constexpr int RS = WAVES / COLGROUPS;
    __shared__ char lds[2 * NPAIR * 8192];

    const int t = threadIdx.x;
    const int w = t >> 6, l = t & 63;
    const int cg = w % COLGROUPS;
    const int rsub = w / COLGROUPS;
    const int l15 = l & 15, lk = (l >> 4) << 3, rq = (l >> 4) << 2;

    const u16* As[3] = {A0, A1, A2};

    int goff[NLOAD], loff[NLOAD];
#pragma unroll
    for (int j = 0; j < NLOAD; ++j) {
        const int p = (j * THREADS) >> 9;
        const int s = ((j * THREADS) & 511) + t;
        goff[j] = s * 8;
        loff[j] = p * 8192 + ((s * 16) ^ (((s >> 4) & 7) << 4));
    }

    bf16x8 bfr[NPAIR][4][2];
#pragma unroll
    for (int p = 0; p < NPAIR; ++p)
#pragma unroll
        for (int ks = 0; ks < 4; ++ks)
#pragma unroll
            for (int cf = 0; cf < 2; ++cf) {
                int n = p * NC + cg * 32 + cf * 16 + l15;
                bfr[p][ks][cf] = *reinterpret_cast<const bf16x8*>(BT + (size_t)n * 128 + ks * 32 + lk);
            }
    const float bv0 = bias[cg * 32 + l15];
    const float bv1 = bias[cg * 32 + 16 + l15];

    u16* ob = outB;
    if (DUAL && cg >= 4) ob = outB2;
    const int colbase = (DUAL ? (cg & 3) : cg) * 32;

    uint4 v[NLOAD];
    int tile = blockIdx.x;
#pragma unroll
    for (int j = 0; j < NLOAD; ++j) {
        const int p = (j * THREADS) >> 9;
        v[j] = *reinterpret_cast<const uint4*>(As[p] + (size_t)tile * 4096 + goff[j]);
    }
#pragma unroll
    for (int j = 0; j < NLOAD; ++j)
        *reinterpret_cast<uint4*>(&lds[loff[j]]) = v[j];
    __syncthreads();

    int buf = 0;
    while (tile < NTILES) {
        const int nxt = tile + (int)gridDim.x;
        if (nxt < NTILES) {
#pragma unroll
            for (int j = 0; j < NLOAD; ++j) {
                const int p = (j * THREADS) >> 9;
                v[j] = *reinterpret_cast<const uint4*>(As[p] + (size_t)nxt * 4096 + goff[j]);
            }
        }

        const int bb = buf * NPAIR * 8192;
        f32x4 acc[2 / RS][2];
#pragma unroll
        for (int rr = 0; rr < 2 / RS; ++rr)
#pragma unroll
            for (int cf = 0; cf < 2; ++cf)
                acc[rr][cf] = f32x4{0.f, 0.f, 0.f, 0.f};
        const int sw = (l15 & 7) << 4;
#pragma unroll
        for (int p = 0; p < NPAIR; ++p) {
            const int base = bb + p * 8192;
#pragma unroll
            for (int ks = 0; ks < 4; ++ks) {
                const int cbyte = ks * 64 + lk * 2;
#pragma unroll
                for (int rr = 0; rr < 2 / RS; ++rr) {
                    const int rf = (RS == 2) ? rsub : rr;
                    bf16x8 a = *reinterpret_cast<const bf16x8*>(
                        &lds[base + (((rf * 16 + l15) * 256 + cbyte) ^ sw)]);
                    acc[rr][0] = __builtin_amdgcn_mfma_f32_16x16x32_bf16(a, bfr[p][ks][0], acc[rr][0], 0, 0, 0);
                    acc[rr][1] = __builtin_amdgcn_mfma_f32_16x16x32_bf16(a, bfr[p][ks][1], acc[rr][1], 0, 0, 0);
                }
            }
        }

        const size_t rowbase = (size_t)tile * 32;
#pragma unroll
        for (int cf = 0; cf < 2; ++cf) {
            const int col = colbase + cf * 16 + l15;
            const float bv = cf ? bv1 : bv0;
#pragma unroll
            for (int rr = 0; rr < 2 / RS; ++rr) {
                const int rf = (RS == 2) ? rsub : rr;
#pragma unroll
                for (int j = 0; j < 4; ++j) {
                    const size_t row = rowbase + rf * 16 + rq + j;
                    float vv = acc[rr][cf][j] + bv;
                    if (RELU) vv = fmaxf(vv, 0.f);
                    if (OUTF32) outF[row * OST + col] = vv;
                    else        ob[row * OST + col] = f2b(vv);
                }
            }
        }

        if (nxt < NTILES) {
            const int ob2 = (buf ^ 1) * NPAIR * 8192;
#pragma unroll
            for (int j = 0; j < NLOAD; ++j)
                *reinterpret_cast<uint4*>(&lds[ob2 + loff[j]]) = v[j];
        }
        __syncthreads();
        buf ^= 1;
        tile = nxt;
    }
}

extern "C" void kernel_launch(void* const* d_in, const int* in_sizes, int n_in,
                              void* d_out, int out_size, void* d_ws, size_t ws_size,
                              hipStream_t stream)
{
    const float* x     = (const float*)d_in[0];
    const int*   src0  = (const int*)d_in[1];
    const int*   dst0  = (const int*)d_in[2];
    const float* ew0   = (const float*)d_in[3];
    const int*   src1  = (const int*)d_in[4];
    const int*   dst1  = (const int*)d_in[5];
    const float* ew1   = (const float*)d_in[6];
    const float* Ws0_0 = (const float*)d_in[7];
    const float* Wn0_0 = (const float*)d_in[8];
    const float* b0_0  = (const float*)d_in[9];
    const float* Wp_0  = (const float*)d_in[10];
    const float* bp_0  = (const float*)d_in[11];
    const float* Ws1_0 = (const float*)d_in[12];
    const float* Wn1_0 = (const float*)d_in[13];
    const float* b1_0  = (const float*)d_in[14];
    const float* Ws0_1 = (const float*)d_in[15];
    const float* Wn0_1 = (const float*)d_in[16];
    const float* b0_1  = (const float*)d_in[17];
    const float* Wp_1  = (const float*)d_in[18];
    const float* bp_1  = (const float*)d_in[19];
    const float* Ws1_1 = (const float*)d_in[20];
    const float* Wn1_1 = (const float*)d_in[21];
    const float* b1_1  = (const float*)d_in[22];

    char* ws = (char*)d_ws;
    u16*   x16   = (u16*)(ws + 0);            // x bf16; reused as hp0 later
    u16*   h16   = (u16*)(ws + 25600000);
    u16*   a0    = (u16*)(ws + 51200000);     // mean-agg r0; reused as max-agg r0
    u16*   a1    = (u16*)(ws + 76800000);     // mean-agg r1; reused as max-agg r1
    u16*   hp1   = (u16*)(ws + 102400000);    // hp r1 bf16
    // stg (76.8MB) aliases h16/a0/a1 regions — all dead during CSR build
    uint2* stg   = (uint2*)(ws + 25600000);
    u32*   csr0  = (u32*)(ws + 128000000);    // NE+8 packed entries
    u32*   csr1  = (u32*)(ws + 130400032);
    int*   offs0 = (int*)(ws + 132800064);
    int*   offs1 = (int*)(ws + 133200080);
    int*   cur0  = (int*)(ws + 133600096);
    int*   cur1  = (int*)(ws + 134000096);
    int*   deg0  = (int*)(ws + 134400096);
    int*   deg1  = (int*)(ws + 134800096);    // contiguous with deg0
    int*   bsA   = (int*)(ws + 135200096);
    int*   bsB   = (int*)(ws + 135200608);
    u16*   wts   = (u16*)(ws + 135201120);
    float* bsum0 = (float*)(ws + 135414112);
    float* bsum1 = (float*)(ws + 135414624);
    float* bpc   = (float*)(ws + 135415136);
    int*   cnt   = (int*)(ws + 135416000);    // 2*NB*8 ints
    u8*    x8    = (u8*)(ws + 136000000);     // x fp8 table (12.8MB)

    u16* hp0 = x16;                           // x16 dead after layer-0 GEMM

    hipMemsetAsync(deg0, 0, 800000, stream);
    bucket_edges<<<2 * NB, 256, 0, stream>>>(
        src0, dst0, ew0, src1, dst1, ew1, stg, cnt);
    deg_from_stg<<<2048, 256, 0, stream>>>(stg, cnt, deg0, deg1);
    scan_local<<<196, 1024, 0, stream>>>(deg0, deg1, offs0, offs1, bsA, bsB);
    scan_bsums<<<2, 128, 0, stream>>>(bsA, bsB);
    scan_add<<<784, 256, 0, stream>>>(offs0, offs1, bsA, bsB, cur0, cur1, csr0, csr1);
    place_csr<<<2048, 256, 0, stream>>>(stg, cnt, cur0, cur1, csr0, csr1);

    fused_setup<<<12918, 256, 0, stream>>>(
        x, x16, x8, Ws0_0, Ws0_1, Wn0_0, Wn0_1, Wp_0, Wp_1,
        Ws1_0, Ws1_1, Wn1_0, Wn1_1, b0_0, b0_1, b1_0, b1_1, bp_0, bp_1,
        wts, bsum0, bsum1, bpc);

    // ---- layer 0: mean gather over fp8 x-table; LDS-staged GEMM ----
    gather<false, true><<<50000, 256, 0, stream>>>(
        x8, x8, offs0, csr0, a0, offs1, csr1, a1);
    gemm_lds<3, 4, 4, true, false, false><<<768, 256, 0, stream>>>(
        x16, a0, a1, wts, bsum0, nullptr, h16, nullptr);

    // ---- layer 1: LDS-staged dual Wp GEMM; max gather; LDS-staged final GEMM ----
    gemm_lds<1, 8, 8, true, false, true><<<768, 512, 0, stream>>>(
        h16, nullptr, nullptr, wts + 49152, bpc, nullptr, hp0, hp1);
    gather<true, false><<<50000, 256, 0, stream>>>(
        (const u8*)hp0, (const u8*)hp1, offs0, csr0, a0, offs1, csr1, a1);
    gemm_lds<3, 2, 4, false, true, false><<<768, 256, 0, stream>>>(
        h16, a0, a1, wts + 81920, bsum1, (float*)d_out, nullptr, nullptr);
}

// Round 22
// 320.037 us; speedup vs baseline: 1.0341x; 1.0341x over previous
//
#include <hip/hip_runtime.h>

typedef short bf16x8 __attribute__((ext_vector_type(8)));
typedef float f32x4 __attribute__((ext_vector_type(4)));
typedef float f32x2 __attribute__((ext_vector_type(2)));
typedef unsigned short u16;
typedef unsigned int u32;
typedef unsigned char u8;

#define NN 100000
#define NE 600000
#define PART 12500        // NN / 8
#define NB 250            // bucket blocks per relation
#define CA 2400           // NE / NB edges per bucket block

__device__ __forceinline__ u16 f2b(float f) {
    u32 u = __float_as_uint(f);
    return (u16)((u + 0x7FFFu + ((u >> 16) & 1u)) >> 16);
}

// ---------------- mega setup: bucket edges | x->bf16+fp8 | weight prep | deg zero ----------------
// Blocks [0,500): bucket edges by dst partition into block-exclusive staging
//   (LDS cursors, no global atomics). Entry: lo=(src<<15)|ew15, hi=dst.
// Blocks [500,13000): x conversions. [13000,13418): weight prep. [13418,14200): zero deg.
// NOTE: cnt must NOT overlap bpc (r21 bug: concurrent sections raced on a 160B overlap).
__global__ void mega_setup(
    const int* __restrict__ src0, const int* __restrict__ dst0,
    const float* __restrict__ ew0,
    const int* __restrict__ src1, const int* __restrict__ dst1,
    const float* __restrict__ ew1,
    uint2* __restrict__ stg, int* __restrict__ cnt,
    const float* __restrict__ x, u16* __restrict__ xo, u8* __restrict__ x8,
    const float* __restrict__ Ws0_0, const float* __restrict__ Ws0_1,
    const float* __restrict__ Wn0_0, const float* __restrict__ Wn0_1,
    const float* __restrict__ Wp_0,  const float* __restrict__ Wp_1,
    const float* __restrict__ Ws1_0, const float* __restrict__ Ws1_1,
    const float* __restrict__ Wn1_0, const float* __restrict__ Wn1_1,
    const float* __restrict__ b0_0, const float* __restrict__ b0_1,
    const float* __restrict__ b1_0, const float* __restrict__ b1_1,
    const float* __restrict__ bp_0, const float* __restrict__ bp_1,
    u16* __restrict__ w, float* __restrict__ bsum0, float* __restrict__ bsum1,
    float* __restrict__ bpc, int* __restrict__ degz)
{
    int bb = blockIdx.x;
    if (bb < 2 * NB) {                        // bucket edges
        int rel = bb >= NB;
        int b = bb - rel * NB;
        const int* src = rel ? src1 : src0;
        const int* dst = rel ? dst1 : dst0;
        const float* ew = rel ? ew1 : ew0;
        __shared__ int lcur[8];
        if (threadIdx.x < 8) lcur[threadIdx.x] = 0;
        __syncthreads();
        uint2* base = stg + (size_t)((rel * NB + b) * 8) * CA;
        const int e0 = b * CA;
        for (int e = e0 + threadIdx.x; e < e0 + CA; e += 256) {
            int d = dst[e];
            int part = d / PART;
            u32 q = (__float_as_uint(ew[e]) + 0x10000u) >> 17;
            u32 lo = ((u32)src[e] << 15) | q;
            int pos = atomicAdd(&lcur[part], 1);
            base[part * CA + pos] = make_uint2(lo, (u32)d);
        }
        __syncthreads();
        if (threadIdx.x < 8)
            cnt[(rel * NB + b) * 8 + threadIdx.x] = lcur[threadIdx.x];
    } else if (bb < 13000) {                  // x -> bf16 + fp8 (12500 blocks)
        int t = (bb - 500) * 256 + threadIdx.x;
        const float4 v = reinterpret_cast<const float4*>(x)[t];
        ushort4 r; r.x = f2b(v.x); r.y = f2b(v.y); r.z = f2b(v.z); r.w = f2b(v.w);
        reinterpret_cast<ushort4*>(xo)[t] = r;
        u32 p = __builtin_amdgcn_cvt_pk_fp8_f32(v.x, v.y, 0, false);
        p = __builtin_amdgcn_cvt_pk_fp8_f32(v.z, v.w, p, true);
        reinterpret_cast<u32*>(x8)[t] = p;
    } else if (bb < 13418) {                  // weight prep (418 blocks)
        int t = (bb - 13000) * 256 + threadIdx.x;
        if (t < 81920) {                      // five 128x128 transposes
            int m = t >> 14, u = t & 16383;
            int n = u >> 7, k = u & 127;
            float v;
            if (m == 0)      v = Ws0_0[k * 128 + n] + Ws0_1[k * 128 + n];
            else if (m == 1) v = Wn0_0[k * 128 + n];
            else if (m == 2) v = Wn0_1[k * 128 + n];
            else if (m == 3) v = Wp_0[k * 128 + n];
            else             v = Wp_1[k * 128 + n];
            w[t] = f2b(v);
        } else if (t < 106496) {              // three 64x128 transposed
            int u = t - 81920;
            int m = u >> 13; u &= 8191;
            int n = u >> 7, k = u & 127;
            float v;
            if (m == 0)      v = Ws1_0[k * 64 + n] + Ws1_1[k * 64 + n];
            else if (m == 1) v = Wn1_0[k * 64 + n];
            else             v = Wn1_1[k * 64 + n];
            w[t] = f2b(v);
        } else if (t < 106624) {
            int i = t - 106496; bsum0[i] = b0_0[i] + b0_1[i];
        } else if (t < 106688) {
            int i = t - 106624; bsum1[i] = b1_0[i] + b1_1[i];
        } else if (t < 106944) {
            int i = t - 106688; bpc[i] = (i < 128) ? bp_0[i] : bp_1[i - 128];
        }
    } else {                                  // zero deg0+deg1 (contiguous 200000 ints)
        int i = (bb - 13418) * 256 + threadIdx.x;
        if (i < 2 * NN) degz[i] = 0;
    }
}

// ---------------- degree count from buckets (XCD-local atomics, co-resident) ----------------
__global__ __launch_bounds__(256) void deg_from_stg(
    const uint2* __restrict__ stg, const int* __restrict__ cnt,
    int* __restrict__ g0, int* __restrict__ g1)
{
    int part = blockIdx.x & 7;
    int sub = blockIdx.x >> 3;                // 0..255
    int rel = sub & 1, idx = sub >> 1;        // idx 0..127
    int* g = rel ? g1 : g0;
    for (int ab = idx * 2; ab < min(idx * 2 + 2, NB); ++ab) {
        int n = cnt[(rel * NB + ab) * 8 + part];
        const uint2* base = stg + (size_t)((rel * NB + ab) * 8 + part) * CA;
        for (int i = threadIdx.x; i < n; i += 256)
            atomicAdd(&g[base[i].y], 1);
    }
}

// ---------------- place entries into CSR (XCD-local atomics) ----------------
__global__ __launch_bounds__(256) void place_csr(
    const uint2* __restrict__ stg, const int* __restrict__ cnt,
    int* __restrict__ cur0, int* __restrict__ cur1,
    u32* __restrict__ csr0, u32* __restrict__ csr1)
{
    int part = blockIdx.x & 7;
    int sub = blockIdx.x >> 3;
    int rel = sub & 1, idx = sub >> 1;
    int* cur = rel ? cur1 : cur0;
    u32* csr = rel ? csr1 : csr0;
    for (int ab = idx * 2; ab < min(idx * 2 + 2, NB); ++ab) {
        int n = cnt[(rel * NB + ab) * 8 + part];
        const uint2* base = stg + (size_t)((rel * NB + ab) * 8 + part) * CA;
        for (int i = threadIdx.x; i < n; i += 256) {
            uint2 en = base[i];
            int p = atomicAdd(&cur[en.y], 1);
            csr[p] = en.x;
        }
    }
}

// ---------------- prefix scan (local pass) ----------------
__global__ void scan_local(const int* __restrict__ deg0, const int* __restrict__ deg1,
                           int* __restrict__ offs0, int* __restrict__ offs1,
                           int* __restrict__ bsA, int* __restrict__ bsB)
{
    __shared__ int sm[1024];
    int rel = blockIdx.x >= 98;
    int blk = blockIdx.x - rel * 98;
    const int* in = rel ? deg1 : deg0;
    int* out = rel ? offs1 : offs0;
    int* bsum = rel ? bsB : bsA;
    int t = threadIdx.x;
    int i = blk * 1024 + t;
    int v = (i < NN) ? in[i] : 0;
    sm[t] = v;
    __syncthreads();
    for (int off = 1; off < 1024; off <<= 1) {
        int add = (t >= off) ? sm[t - off] : 0;
        __syncthreads();
        sm[t] += add;
        __syncthreads();
    }
    if (i < NN) out[i] = sm[t] - v;            // exclusive within block
    if (t == 1023) bsum[blk] = sm[1023];       // raw block totals
}

// ---------------- scan finalize: re-scan 98 raw block-sums in LDS + add ----------------
__global__ void scan_add(int* __restrict__ offs0, int* __restrict__ offs1,
                         const int* __restrict__ bsA, const int* __restrict__ bsB,
                         int* __restrict__ cur0, int* __restrict__ cur1,
                         u32* __restrict__ csr0, u32* __restrict__ csr1)
{
    int rel = blockIdx.x >= 392;
    int i = (blockIdx.x - rel * 392) * 256 + threadIdx.x;
    int* offs = rel ? offs1 : offs0;
    int* cur = rel ? cur1 : cur0;
    const int* bsum = rel ? bsB : bsA;
    __shared__ int sm[128];
    int t = threadIdx.x;
    if (t < 128) sm[t] = (t < 98) ? bsum[t] : 0;
    __syncthreads();
    for (int off = 1; off < 128; off <<= 1) {
        int add = (t >= off && t < 128) ? sm[t - off] : 0;
        __syncthreads();
        if (t < 128) sm[t] += add;
        __syncthreads();
    }
    if (i < NN) {
        int blk = i >> 10;
        int v = offs[i] + (blk ? sm[blk - 1] : 0);
        offs[i] = v;
        cur[i] = v;
    }
    if (i == 0) offs[NN] = NE;
    if (blockIdx.x == 0 && threadIdx.x < 8) {  // pads for gather unroll-8 over-read
        csr0[NE + threadIdx.x] = 0;
        csr1[NE + threadIdx.x] = 0;
    }
}

// ---------------- flat gather, wave per node, unroll-8 ----------------
// FP8: table rows 128B fp8 e4m3 (mean path); else bf16 256B rows (max path).
template<bool MAXAGG, bool FP8>
__global__ __launch_bounds__(256) void gather(
    const u8* __restrict__ F0, const u8* __restrict__ F1,
    const int* __restrict__ offs0, const u32* __restrict__ csr0, u16* __restrict__ o0,
    const int* __restrict__ offs1, const u32* __restrict__ csr1, u16* __restrict__ o1)
{
    int b = blockIdx.x;
    int rel = b >= 25000;
    const u8* F = rel ? F1 : F0;
    const int* offs = rel ? offs1 : offs0;
    const u32* csr = rel ? csr1 : csr0;
    u16* out = rel ? o1 : o0;
    int node = (b - rel * 25000) * 4 + (threadIdx.x >> 6);
    int lane2 = (threadIdx.x & 63) << 1;       // 2 features per lane
    int beg = __builtin_amdgcn_readfirstlane(offs[node]);
    int end = __builtin_amdgcn_readfirstlane(offs[node + 1]);

    float a0 = 0.f, a1 = 0.f;
    for (int e = beg; e < end; e += 8) {
        u32 E[8], v[8];
#pragma unroll
        for (int i = 0; i < 8; ++i)
            E[i] = csr[e + i];
#pragma unroll
        for (int i = 0; i < 8; ++i) {
            if (FP8)
                v[i] = *reinterpret_cast<const u16*>(F + ((size_t)(E[i] >> 15) << 7) + lane2);
            else
                v[i] = *reinterpret_cast<const u32*>(F + ((size_t)(E[i] >> 15) << 8) + (lane2 << 1));
        }
#pragma unroll
        for (int i = 0; i < 8; ++i) {
            float wgt = (e + i < end) ? __uint_as_float(E[i] << 17) : 0.f;
            float f0, f1;
            if (FP8) {
                f32x2 d = __builtin_amdgcn_cvt_pk_f32_fp8(v[i], false);
                f0 = d.x; f1 = d.y;
            } else {
                f0 = __uint_as_float(v[i] << 16);
                f1 = __uint_as_float(v[i] & 0xFFFF0000u);
            }
            if (MAXAGG) { a0 = fmaxf(a0, f0 * wgt); a1 = fmaxf(a1, f1 * wgt); }
            else        { a0 = fmaf(f0, wgt, a0);   a1 = fmaf(f1, wgt, a1); }
        }
    }
    float s = MAXAGG ? 1.f : 1.f / fmaxf((float)(end - beg), 1.f);
    ushort2 r; r.x = f2b(a0 * s); r.y = f2b(a1 * s);
    *reinterpret_cast<ushort2*>(out + (size_t)node * 128 + lane2) = r;
}

// ---------------- LDS-staged double-buffered MFMA GEMM ----------------
// A tiles staged reg->LDS with async split (issue loads before compute, write after).
// XOR swizzle byte ^= (row&7)<<4; RS=WAVES/COLGROUPS row split.
template<int NPAIR, int COLGROUPS, int WAVES, bool RELU, bool OUTF32, bool DUAL>
__global__ __launch_bounds__(WAVES * 64) void gemm_lds(
    const u16* __restrict__ A0, const u16* __restrict__ A1, const u16* __restrict__ A2,
    const u16* __restrict__ BT, const float* __restrict__ bias,
    float* __restrict__ outF, u16* __restrict__ outB, u16* __restrict__ outB2)
{
    constexpr int NC = COLGROUPS * 32;
    constexpr int OST = DUAL ? (NC / 2) : NC;
    constexpr int NTILES = NN / 32;
    constexpr int THREADS = WAVES * 64;
    constexpr int NLOAD = NPAIR * 512 / THREADS;
    constexpr int RS = WAVES / COLGROUPS;
    __shared__ char lds[2 * NPAIR * 8192];

    const int t = threadIdx.x;
    const int w = t >> 6, l = t & 63;
    const int cg = w % COLGROUPS;
    const int rsub = w / COLGROUPS;
    const int l15 = l & 15, lk = (l >> 4) << 3, rq = (l >> 4) << 2;

    const u16* As[3] = {A0, A1, A2};

    int goff[NLOAD], loff[NLOAD];
#pragma unroll
    for (int j = 0; j < NLOAD; ++j) {
        const int p = (j * THREADS) >> 9;
        const int s = ((j * THREADS) & 511) + t;
        goff[j] = s * 8;
        loff[j] = p * 8192 + ((s * 16) ^ (((s >> 4) & 7) << 4));
    }

    bf16x8 bfr[NPAIR][4][2];
#pragma unroll
    for (int p = 0; p < NPAIR; ++p)
#pragma unroll
        for (int ks = 0; ks < 4; ++ks)
#pragma unroll
            for (int cf = 0; cf < 2; ++cf) {
                int n = p * NC + cg * 32 + cf * 16 + l15;
                bfr[p][ks][cf] = *reinterpret_cast<const bf16x8*>(BT + (size_t)n * 128 + ks * 32 + lk);
            }
    const float bv0 = bias[cg * 32 + l15];
    const float bv1 = bias[cg * 32 + 16 + l15];

    u16* ob = outB;
    if (DUAL && cg >= 4) ob = outB2;
    const int colbase = (DUAL ? (cg & 3) : cg) * 32;

    uint4 v[NLOAD];
    int tile = blockIdx.x;
#pragma unroll
    for (int j = 0; j < NLOAD; ++j) {
        const int p = (j * THREADS) >> 9;
        v[j] = *reinterpret_cast<const uint4*>(As[p] + (size_t)tile * 4096 + goff[j]);
    }
#pragma unroll
    for (int j = 0; j < NLOAD; ++j)
        *reinterpret_cast<uint4*>(&lds[loff[j]]) = v[j];
    __syncthreads();

    int buf = 0;
    while (tile < NTILES) {
        const int nxt = tile + (int)gridDim.x;
        if (nxt < NTILES) {
#pragma unroll
            for (int j = 0; j < NLOAD; ++j) {
                const int p = (j * THREADS) >> 9;
                v[j] = *reinterpret_cast<const uint4*>(As[p] + (size_t)nxt * 4096 + goff[j]);
            }
        }

        const int bb = buf * NPAIR * 8192;
        f32x4 acc[2 / RS][2];
#pragma unroll
        for (int rr = 0; rr < 2 / RS; ++rr)
#pragma unroll
            for (int cf = 0; cf < 2; ++cf)
                acc[rr][cf] = f32x4{0.f, 0.f, 0.f, 0.f};
        const int sw = (l15 & 7) << 4;
#pragma unroll
        for (int p = 0; p < NPAIR; ++p) {
            const int base = bb + p * 8192;
#pragma unroll
            for (int ks = 0; ks < 4; ++ks) {
                const int cbyte = ks * 64 + lk * 2;
#pragma unroll
                for (int rr = 0; rr < 2 / RS; ++rr) {
                    const int rf = (RS == 2) ? rsub : rr;
                    bf16x8 a = *reinterpret_cast<const bf16x8*>(
                        &lds[base + (((rf * 16 + l15) * 256 + cbyte) ^ sw)]);
                    acc[rr][0] = __builtin_amdgcn_mfma_f32_16x16x32_bf16(a, bfr[p][ks][0], acc[rr][0], 0, 0, 0);
                    acc[rr][1] = __builtin_amdgcn_mfma_f32_16x16x32_bf16(a, bfr[p][ks][1], acc[rr][1], 0, 0, 0);
                }
            }
        }

        const size_t rowbase = (size_t)tile * 32;
#pragma unroll
        for (int cf = 0; cf < 2; ++cf) {
            const int col = colbase + cf * 16 + l15;
            const float bv = cf ? bv1 : bv0;
#pragma unroll
            for (int rr = 0; rr < 2 / RS; ++rr) {
                const int rf = (RS == 2) ? rsub : rr;
#pragma unroll
                for (int j = 0; j < 4; ++j) {
                    const size_t row = rowbase + rf * 16 + rq + j;
                    float vv = acc[rr][cf][j] + bv;
                    if (RELU) vv = fmaxf(vv, 0.f);
                    if (OUTF32) outF[row * OST + col] = vv;
                    else        ob[row * OST + col] = f2b(vv);
                }
            }
        }

        if (nxt < NTILES) {
            const int ob2 = (buf ^ 1) * NPAIR * 8192;
#pragma unroll
            for (int j = 0; j < NLOAD; ++j)
                *reinterpret_cast<uint4*>(&lds[ob2 + loff[j]]) = v[j];
        }
        __syncthreads();
        buf ^= 1;
        tile = nxt;
    }
}

extern "C" void kernel_launch(void* const* d_in, const int* in_sizes, int n_in,
                              void* d_out, int out_size, void* d_ws, size_t ws_size,
                              hipStream_t stream)
{
    const float* x     = (const float*)d_in[0];
    const int*   src0  = (const int*)d_in[1];
    const int*   dst0  = (const int*)d_in[2];
    const float* ew0   = (const float*)d_in[3];
    const int*   src1  = (const int*)d_in[4];
    const int*   dst1  = (const int*)d_in[5];
    const float* ew1   = (const float*)d_in[6];
    const float* Ws0_0 = (const float*)d_in[7];
    const float* Wn0_0 = (const float*)d_in[8];
    const float* b0_0  = (const float*)d_in[9];
    const float* Wp_0  = (const float*)d_in[10];
    const float* bp_0  = (const float*)d_in[11];
    const float* Ws1_0 = (const float*)d_in[12];
    const float* Wn1_0 = (const float*)d_in[13];
    const float* b1_0  = (const float*)d_in[14];
    const float* Ws0_1 = (const float*)d_in[15];
    const float* Wn0_1 = (const float*)d_in[16];
    const float* b0_1  = (const float*)d_in[17];
    const float* Wp_1  = (const float*)d_in[18];
    const float* bp_1  = (const float*)d_in[19];
    const float* Ws1_1 = (const float*)d_in[20];
    const float* Wn1_1 = (const float*)d_in[21];
    const float* b1_1  = (const float*)d_in[22];

    char* ws = (char*)d_ws;
    u16*   x16   = (u16*)(ws + 0);            // x bf16; reused as hp0 later
    u16*   h16   = (u16*)(ws + 25600000);
    u16*   a0    = (u16*)(ws + 51200000);     // mean-agg r0; reused as max-agg r0
    u16*   a1    = (u16*)(ws + 76800000);     // mean-agg r1; reused as max-agg r1
    u16*   hp1   = (u16*)(ws + 102400000);    // hp r1 bf16
    // stg (76.8MB) aliases h16/a0/a1 regions — all dead during CSR build
    uint2* stg   = (uint2*)(ws + 25600000);
    u32*   csr0  = (u32*)(ws + 128000000);    // NE+8 packed entries
    u32*   csr1  = (u32*)(ws + 130400032);
    int*   offs0 = (int*)(ws + 132800064);
    int*   offs1 = (int*)(ws + 133200080);
    int*   cur0  = (int*)(ws + 133600096);
    int*   cur1  = (int*)(ws + 134000096);
    int*   deg0  = (int*)(ws + 134400096);
    int*   deg1  = (int*)(ws + 134800096);    // contiguous with deg0
    int*   bsA   = (int*)(ws + 135200096);
    int*   bsB   = (int*)(ws + 135200608);
    u16*   wts   = (u16*)(ws + 135201120);
    float* bsum0 = (float*)(ws + 135414112);
    float* bsum1 = (float*)(ws + 135414624);
    float* bpc   = (float*)(ws + 135415136);  // 256 floats -> ends 135416160
    int*   cnt   = (int*)(ws + 135420000);    // 2*NB*8 ints (past bpc; r21 overlap fixed)
    u8*    x8    = (u8*)(ws + 136000000);     // x fp8 table (12.8MB)

    u16* hp0 = x16;                           // x16 dead after layer-0 GEMM

    mega_setup<<<14200, 256, 0, stream>>>(
        src0, dst0, ew0, src1, dst1, ew1, stg, cnt,
        x, x16, x8, Ws0_0, Ws0_1, Wn0_0, Wn0_1, Wp_0, Wp_1,
        Ws1_0, Ws1_1, Wn1_0, Wn1_1, b0_0, b0_1, b1_0, b1_1, bp_0, bp_1,
        wts, bsum0, bsum1, bpc, deg0);

    deg_from_stg<<<2048, 256, 0, stream>>>(stg, cnt, deg0, deg1);
    scan_local<<<196, 1024, 0, stream>>>(deg0, deg1, offs0, offs1, bsA, bsB);
    scan_add<<<784, 256, 0, stream>>>(offs0, offs1, bsA, bsB, cur0, cur1, csr0, csr1);
    place_csr<<<2048, 256, 0, stream>>>(stg, cnt, cur0, cur1, csr0, csr1);

    // ---- layer 0: mean gather over fp8 x-table; LDS-staged GEMM ----
    gather<false, true><<<50000, 256, 0, stream>>>(
        x8, x8, offs0, csr0, a0, offs1, csr1, a1);
    gemm_lds<3, 4, 4, true, false, false><<<768, 256, 0, stream>>>(
        x16, a0, a1, wts, bsum0, nullptr, h16, nullptr);

    // ---- layer 1: LDS-staged dual Wp GEMM; max gather; LDS-staged final GEMM ----
    gemm_lds<1, 8, 8, true, false, true><<<768, 512, 0, stream>>>(
        h16, nullptr, nullptr, wts + 49152, bpc, nullptr, hp0, hp1);
    gather<true, false><<<50000, 256, 0, stream>>>(
        (const u8*)hp0, (const u8*)hp1, offs0, csr0, a0, offs1, csr1, a1);
    gemm_lds<3, 2, 4, false, true, false><<<768, 256, 0, stream>>>(
        h16, a0, a1, wts + 81920, bsum1, (float*)d_out, nullptr, nullptr);
}